// Round 1
// baseline (462.667 us; speedup 1.0000x reference)
//
#include <hip/hip_runtime.h>
#include <stdint.h>

typedef __attribute__((ext_vector_type(8))) short short8;      // 8 x bf16 (4 VGPRs) MFMA A/B frag
typedef __attribute__((ext_vector_type(4))) float f32x4;       // MFMA C/D frag
typedef __attribute__((ext_vector_type(4))) unsigned short u16x4;

typedef unsigned short ushort_t;

__device__ __forceinline__ unsigned short f2bf(float f) {
    union { float f; uint32_t u; } c; c.f = f;
    uint32_t u = c.u;
    return (unsigned short)((u + 0x7FFFu + ((u >> 16) & 1u)) >> 16);   // RNE
}

__device__ __forceinline__ f32x4 mfma16(short8 a, short8 b, f32x4 c) {
    return __builtin_amdgcn_mfma_f32_16x16x32_bf16(a, b, c, 0, 0, 0);
}

// ---------------- converters ----------------

__global__ __launch_bounds__(256) void cvt_x_k(const float4* __restrict__ in,
                                               u16x4* __restrict__ out, int n4) {
    int i = blockIdx.x * 256 + threadIdx.x;
    if (i < n4) {
        float4 v = in[i];
        u16x4 o;
        o[0] = f2bf(v.x); o[1] = f2bf(v.y); o[2] = f2bf(v.z); o[3] = f2bf(v.w);
        out[i] = o;
    }
}

// kv_w (131072 groups) + proj_w (65536) + q_global*scale (100352) = 296960 groups
__global__ __launch_bounds__(256) void cvt_small_k(const float4* __restrict__ kvw,
                                                   const float4* __restrict__ pw,
                                                   const float4* __restrict__ qg,
                                                   u16x4* __restrict__ kvwb,
                                                   u16x4* __restrict__ pwb,
                                                   u16x4* __restrict__ qb) {
    const float qs = 0.17677669529663687f;  // 32^-0.5
    int i = blockIdx.x * 256 + threadIdx.x;
    if (i < 131072) {
        float4 v = kvw[i];
        u16x4 o; o[0]=f2bf(v.x); o[1]=f2bf(v.y); o[2]=f2bf(v.z); o[3]=f2bf(v.w);
        kvwb[i] = o;
    } else if (i < 196608) {
        int j = i - 131072;
        float4 v = pw[j];
        u16x4 o; o[0]=f2bf(v.x); o[1]=f2bf(v.y); o[2]=f2bf(v.z); o[3]=f2bf(v.w);
        pwb[j] = o;
    } else {
        int j = i - 196608;   // < 100352
        float4 v = qg[j];
        u16x4 o; o[0]=f2bf(v.x*qs); o[1]=f2bf(v.y*qs); o[2]=f2bf(v.z*qs); o[3]=f2bf(v.w*qs);
        qb[j] = o;
    }
}

// bias_full[h][i][j], i,j in [0,208); -1e30 on pad so softmax masks pad keys
__global__ __launch_bounds__(256) void bias_k(const float* __restrict__ bt,
                                              float* __restrict__ out) {
    int idx = blockIdx.x * 256 + threadIdx.x;        // 16*208*208 = 692224 exact
    int h = idx / 43264;
    int rem = idx - h * 43264;
    int i = rem / 208;
    int j = rem - i * 208;
    float v = -1e30f;
    if (i < 196 && j < 196) {
        int t1 = i / 49, r1 = i - t1 * 49, h1 = r1 / 7, w1 = r1 - h1 * 7;
        int t2 = j / 49, r2 = j - t2 * 49, h2 = r2 / 7, w2 = r2 - h2 * 7;
        int bi = (t1 - t2 + 3) * 169 + (h1 - h2 + 6) * 13 + (w1 - w2 + 6);
        v = bt[bi * 16 + h];
    }
    out[idx] = v;
}

// ---------------- KV projection GEMM ----------------
// A: x_bf16 [50176][512], B: kv_w_bf16 [1024][512] (B^T form: D = A.B^T)
// tile 128x128, BK=64, 4 waves (2x2), each 64x64. LDS stride 72 => conflict-free.
__global__ __launch_bounds__(256) void gemm_kv(const ushort_t* __restrict__ A,
                                               const ushort_t* __restrict__ Bw,
                                               const float* __restrict__ kvb,
                                               ushort_t* __restrict__ Ko,
                                               ushort_t* __restrict__ Vo) {
    __shared__ ushort_t As[128 * 72];
    __shared__ ushort_t Bs[128 * 72];
    const int tid = threadIdx.x;
    const int lane = tid & 63, wave = tid >> 6;
    const int lrow = lane & 15, quad = lane >> 4;
    const int wr = wave >> 1, wc = wave & 1;
    const long arow0 = (long)blockIdx.x * 128;
    const int brow0 = blockIdx.y * 128;

    f32x4 acc[4][4];
#pragma unroll
    for (int i = 0; i < 4; ++i)
#pragma unroll
        for (int j = 0; j < 4; ++j) acc[i][j] = (f32x4){0.f, 0.f, 0.f, 0.f};

    for (int k0 = 0; k0 < 512; k0 += 64) {
        short8 ar[4], br[4];
#pragma unroll
        for (int it = 0; it < 4; ++it) {
            int c = it * 256 + tid;
            int row = c >> 3, cc = c & 7;
            ar[it] = *(const short8*)&A[(arow0 + row) * 512 + k0 + cc * 8];
            br[it] = *(const short8*)&Bw[(long)(brow0 + row) * 512 + k0 + cc * 8];
        }
        __syncthreads();
#pragma unroll
        for (int it = 0; it < 4; ++it) {
            int c = it * 256 + tid;
            int row = c >> 3, cc = c & 7;
            *(short8*)&As[row * 72 + cc * 8] = ar[it];
            *(short8*)&Bs[row * 72 + cc * 8] = br[it];
        }
        __syncthreads();
#pragma unroll
        for (int kk = 0; kk < 64; kk += 32) {
            short8 af[4], bf[4];
#pragma unroll
            for (int i = 0; i < 4; ++i)
                af[i] = *(const short8*)&As[(wr * 64 + i * 16 + lrow) * 72 + kk + quad * 8];
#pragma unroll
            for (int j = 0; j < 4; ++j)
                bf[j] = *(const short8*)&Bs[(wc * 64 + j * 16 + lrow) * 72 + kk + quad * 8];
#pragma unroll
            for (int i = 0; i < 4; ++i)
#pragma unroll
                for (int j = 0; j < 4; ++j)
                    acc[i][j] = mfma16(af[i], bf[j], acc[i][j]);
        }
    }
    // epilogue: scatter to K/V [b_,h,n,d] bf16, + kv_b
#pragma unroll
    for (int i = 0; i < 4; ++i) {
        int mb = (int)arow0 + wr * 64 + i * 16 + quad * 4;
#pragma unroll
        for (int r = 0; r < 4; ++r) {
            int m = mb + r;
            int b_ = m / 196;
            int n = m - b_ * 196;
#pragma unroll
            for (int j = 0; j < 4; ++j) {
                int cI = brow0 + wc * 64 + j * 16 + lrow;
                float v = acc[i][j][r] + kvb[cI];
                int hh = (cI >> 5) & 15, d = cI & 31;
                ushort_t* dst = (cI >> 9) ? Vo : Ko;
                dst[((((long)b_ << 4) + hh) * 196 + n) * 32 + d] = f2bf(v);
            }
        }
    }
}

// ---------------- fused attention ----------------
// one block per (b_, h); 4 waves, row-tiles rt = wave, wave+4, ...
__global__ __launch_bounds__(256) void attn_k(const ushort_t* __restrict__ Kb,
                                              const ushort_t* __restrict__ Vb,
                                              const ushort_t* __restrict__ Qb,
                                              const float* __restrict__ biasF,
                                              ushort_t* __restrict__ Ob) {
    const int tid = threadIdx.x, lane = tid & 63, wave = tid >> 6;
    const int lrow = lane & 15, quad = lane >> 4;
    const int bh = blockIdx.x;           // = b_*16 + h
    const int b_ = bh >> 4, h = bh & 15;
    const int Bq = b_ >> 6;              // B_dim = 64

    __shared__ ushort_t Ks[208 * 40];    // [n][d], stride 40 (conflict-free b128)
    __shared__ ushort_t Vt[32 * 232];    // [d][j], stride 232
    __shared__ ushort_t Ps[4][16 * 232]; // per-wave P scratch [m][j]

    const long kvoff = (long)bh * 6272;  // 196*32

    for (int c = tid; c < 784; c += 256) {           // K -> LDS (16B chunks)
        int n = c >> 2, dp = c & 3;
        *(short8*)&Ks[n * 40 + dp * 8] = *(const short8*)&Kb[kvoff + n * 32 + dp * 8];
    }
    for (int i = tid; i < 12 * 40; i += 256) Ks[196 * 40 + i] = 0;   // pad rows
    for (int i = tid; i < 6272; i += 256) {          // V -> LDS transposed
        int n = i >> 5, d = i & 31;
        Vt[d * 232 + n] = Vb[kvoff + i];
    }
    for (int i = tid; i < 32 * 36; i += 256) {       // V^T pad cols
        int d = i / 36, j = i - d * 36;
        Vt[d * 232 + 196 + j] = 0;
    }
    for (int i = lane; i < 256; i += 64) {           // P pad cols 208..223 (per wave)
        int r = i >> 4, cp = i & 15;
        Ps[wave][r * 232 + 208 + cp] = 0;
    }
    __syncthreads();

    const float* biasH = biasF + h * 43264;
    const long qbase = (((long)Bq * 16 + h) * 196) * 32;

    for (int rt = wave; rt < 13; rt += 4) {
        int qrow = rt * 16 + lrow; if (qrow > 195) qrow = 195;
        short8 qf = *(const short8*)&Qb[qbase + (long)qrow * 32 + quad * 8];

        f32x4 s[13];
#pragma unroll
        for (int ct = 0; ct < 13; ++ct) {
            short8 kf = *(const short8*)&Ks[(ct * 16 + lrow) * 40 + quad * 8];
            s[ct] = mfma16(qf, kf, (f32x4){0.f, 0.f, 0.f, 0.f});
        }
        const int srow0 = rt * 16 + quad * 4;
        float mx[4], sm[4];
#pragma unroll
        for (int r = 0; r < 4; ++r) mx[r] = -3e38f;
#pragma unroll
        for (int ct = 0; ct < 13; ++ct) {
            const float* bp = biasH + (long)srow0 * 208 + ct * 16 + lrow;
#pragma unroll
            for (int r = 0; r < 4; ++r) {
                float v = s[ct][r] + bp[r * 208];
                s[ct][r] = v;
                mx[r] = fmaxf(mx[r], v);
            }
        }
#pragma unroll
        for (int r = 0; r < 4; ++r) {
            mx[r] = fmaxf(mx[r], __shfl_xor(mx[r], 1, 16));
            mx[r] = fmaxf(mx[r], __shfl_xor(mx[r], 2, 16));
            mx[r] = fmaxf(mx[r], __shfl_xor(mx[r], 4, 16));
            mx[r] = fmaxf(mx[r], __shfl_xor(mx[r], 8, 16));
            sm[r] = 0.f;
        }
#pragma unroll
        for (int ct = 0; ct < 13; ++ct)
#pragma unroll
            for (int r = 0; r < 4; ++r) {
                float p = __expf(s[ct][r] - mx[r]);
                s[ct][r] = p;
                sm[r] += p;
            }
#pragma unroll
        for (int r = 0; r < 4; ++r) {
            sm[r] += __shfl_xor(sm[r], 1, 16);
            sm[r] += __shfl_xor(sm[r], 2, 16);
            sm[r] += __shfl_xor(sm[r], 4, 16);
            sm[r] += __shfl_xor(sm[r], 8, 16);
            sm[r] = 1.0f / sm[r];
        }
        ushort_t* prow = &Ps[wave][0];
#pragma unroll
        for (int ct = 0; ct < 13; ++ct)
#pragma unroll
            for (int r = 0; r < 4; ++r)
                prow[(quad * 4 + r) * 232 + ct * 16 + lrow] = f2bf(s[ct][r] * sm[r]);
        asm volatile("s_waitcnt lgkmcnt(0)" ::: "memory");  // in-wave LDS RAW fence

        f32x4 o0 = (f32x4){0.f,0.f,0.f,0.f}, o1 = (f32x4){0.f,0.f,0.f,0.f};
#pragma unroll
        for (int ks = 0; ks < 7; ++ks) {
            short8 pf = *(const short8*)&prow[lrow * 232 + ks * 32 + quad * 8];
            short8 v0 = *(const short8*)&Vt[lrow * 232 + ks * 32 + quad * 8];
            short8 v1 = *(const short8*)&Vt[(16 + lrow) * 232 + ks * 32 + quad * 8];
            o0 = mfma16(pf, v0, o0);
            o1 = mfma16(pf, v1, o1);
        }
        const long obase = (long)b_ * 196 * 512 + h * 32;
#pragma unroll
        for (int r = 0; r < 4; ++r) {
            int m = srow0 + r;
            if (m < 196) {
                Ob[obase + (long)m * 512 + lrow]      = f2bf(o0[r]);
                Ob[obase + (long)m * 512 + 16 + lrow] = f2bf(o1[r]);
            }
        }
    }
}

// ---------------- output projection GEMM ----------------
__global__ __launch_bounds__(256) void gemm_proj(const ushort_t* __restrict__ A,
                                                 const ushort_t* __restrict__ Bw,
                                                 const float* __restrict__ pb,
                                                 float* __restrict__ out) {
    __shared__ ushort_t As[128 * 72];
    __shared__ ushort_t Bs[128 * 72];
    const int tid = threadIdx.x;
    const int lane = tid & 63, wave = tid >> 6;
    const int lrow = lane & 15, quad = lane >> 4;
    const int wr = wave >> 1, wc = wave & 1;
    const long arow0 = (long)blockIdx.x * 128;
    const int brow0 = blockIdx.y * 128;

    f32x4 acc[4][4];
#pragma unroll
    for (int i = 0; i < 4; ++i)
#pragma unroll
        for (int j = 0; j < 4; ++j) acc[i][j] = (f32x4){0.f, 0.f, 0.f, 0.f};

    for (int k0 = 0; k0 < 512; k0 += 64) {
        short8 ar[4], br[4];
#pragma unroll
        for (int it = 0; it < 4; ++it) {
            int c = it * 256 + tid;
            int row = c >> 3, cc = c & 7;
            ar[it] = *(const short8*)&A[(arow0 + row) * 512 + k0 + cc * 8];
            br[it] = *(const short8*)&Bw[(long)(brow0 + row) * 512 + k0 + cc * 8];
        }
        __syncthreads();
#pragma unroll
        for (int it = 0; it < 4; ++it) {
            int c = it * 256 + tid;
            int row = c >> 3, cc = c & 7;
            *(short8*)&As[row * 72 + cc * 8] = ar[it];
            *(short8*)&Bs[row * 72 + cc * 8] = br[it];
        }
        __syncthreads();
#pragma unroll
        for (int kk = 0; kk < 64; kk += 32) {
            short8 af[4], bf[4];
#pragma unroll
            for (int i = 0; i < 4; ++i)
                af[i] = *(const short8*)&As[(wr * 64 + i * 16 + lrow) * 72 + kk + quad * 8];
#pragma unroll
            for (int j = 0; j < 4; ++j)
                bf[j] = *(const short8*)&Bs[(wc * 64 + j * 16 + lrow) * 72 + kk + quad * 8];
#pragma unroll
            for (int i = 0; i < 4; ++i)
#pragma unroll
                for (int j = 0; j < 4; ++j)
                    acc[i][j] = mfma16(af[i], bf[j], acc[i][j]);
        }
    }
#pragma unroll
    for (int i = 0; i < 4; ++i) {
        long mb = arow0 + wr * 64 + i * 16 + quad * 4;
#pragma unroll
        for (int r = 0; r < 4; ++r) {
            long m = mb + r;
#pragma unroll
            for (int j = 0; j < 4; ++j) {
                int cI = brow0 + wc * 64 + j * 16 + lrow;
                out[m * 512 + cI] = acc[i][j][r] + pb[cI];
            }
        }
    }
}

// ---------------- launch ----------------

extern "C" void kernel_launch(void* const* d_in, const int* in_sizes, int n_in,
                              void* d_out, int out_size, void* d_ws, size_t ws_size,
                              hipStream_t stream) {
    const float* x   = (const float*)d_in[0];
    const float* qg  = (const float*)d_in[1];
    const float* kvw = (const float*)d_in[2];
    const float* kvb = (const float*)d_in[3];
    const float* pw  = (const float*)d_in[4];
    const float* pb  = (const float*)d_in[5];
    const float* bt  = (const float*)d_in[6];
    float* out = (float*)d_out;

    char* ws = (char*)d_ws;
    ushort_t* xb    = (ushort_t*)(ws);                 // 51,380,224 B  (also aliased as attn out)
    ushort_t* kbuf  = (ushort_t*)(ws + 51380224);      // 51,380,224 B
    ushort_t* vbuf  = (ushort_t*)(ws + 102760448);     // 51,380,224 B
    ushort_t* kvwb  = (ushort_t*)(ws + 154140672);     //  1,048,576 B
    ushort_t* pwb   = (ushort_t*)(ws + 155189248);     //    524,288 B
    ushort_t* qb    = (ushort_t*)(ws + 155713536);     //    802,816 B
    float*    biasF = (float*)   (ws + 156516352);     //  2,768,896 B -> total 159,285,248 B
    ushort_t* obuf  = xb;  // x dead after gemm_kv; reuse for attention output

    cvt_x_k<<<25088, 256, 0, stream>>>((const float4*)x, (u16x4*)xb, 6422528);
    cvt_small_k<<<1160, 256, 0, stream>>>((const float4*)kvw, (const float4*)pw,
                                          (const float4*)qg,
                                          (u16x4*)kvwb, (u16x4*)pwb, (u16x4*)qb);
    bias_k<<<2704, 256, 0, stream>>>(bt, biasF);
    gemm_kv<<<dim3(392, 8), 256, 0, stream>>>(xb, kvwb, kvb, kbuf, vbuf);
    attn_k<<<4096, 256, 0, stream>>>(kbuf, vbuf, qb, biasF, obuf);
    gemm_proj<<<dim3(392, 4), 256, 0, stream>>>(obuf, pwb, pb, out);
}